// Round 1
// baseline (100.730 us; speedup 1.0000x reference)
//
#include <hip/hip_runtime.h>
#include <hip/hip_bf16.h>
#include <math.h>

typedef __bf16 bf16;
typedef __attribute__((ext_vector_type(4))) float f32x4;
typedef __attribute__((ext_vector_type(8))) bf16 bf16x8;
typedef __attribute__((ext_vector_type(4))) bf16 bf16x4;

#define M_TOT 16384
#define K_TOT 1024
#define E_TOT 1024   // 512 mu + 512 logvar
#define D_EMB 512
#define BM 128
#define BN 128
#define BK 32
#define LDS_STRIDE 40  // 32 + 8 pad: 80B rows, 16B aligned, 2-way-bank-conflict only

// C[m,e] = sum_k x[m,k] * W[e,k]; e<512 -> mu head, e>=512 -> logvar head.
__global__ __launch_bounds__(256) void gpe_gemm(
    const float* __restrict__ x,
    const float* __restrict__ W_mu,
    const float* __restrict__ b_mu,
    const float* __restrict__ W_logvar,
    const float* __restrict__ b_logvar,
    float* __restrict__ out)
{
    __shared__ __align__(16) bf16 As[BM][LDS_STRIDE];
    __shared__ __align__(16) bf16 Bs[BN][LDS_STRIDE];

    const int tid  = threadIdx.x;
    const int lane = tid & 63;
    const int wid  = tid >> 6;
    const int wr   = wid >> 1;   // 0..1 : wave row (64 rows each)
    const int wc   = wid & 1;    // 0..1 : wave col (64 cols each)

    const int bn = blockIdx.x & 7;    // E_TOT/BN = 8, inner: consecutive blocks share A panel
    const int bm = blockIdx.x >> 3;

    const int ebase = bn * BN;
    const bool is_mu = (ebase < D_EMB);
    const float* __restrict__ Wp = is_mu ? (W_mu + (size_t)ebase * K_TOT)
                                         : (W_logvar + (size_t)(ebase - D_EMB) * K_TOT);
    const float* __restrict__ bias = is_mu ? b_mu : b_logvar;
    const int cbase = is_mu ? ebase : (ebase - D_EMB);
    float* __restrict__ obase = is_mu ? out : (out + (size_t)M_TOT * D_EMB);

    const float* __restrict__ Ap = x + (size_t)(bm * BM) * K_TOT;

    f32x4 acc[4][4];
#pragma unroll
    for (int m = 0; m < 4; ++m)
#pragma unroll
        for (int n = 0; n < 4; ++n)
            acc[m][n] = (f32x4){0.f, 0.f, 0.f, 0.f};

    // fragment LDS addresses (constant over K loop)
    const int fr = lane & 15;          // A row / B col within 16x16 fragment
    const int fk = (lane >> 4) * 8;    // k offset: 8 contiguous bf16
    const int arow = wr * 64 + fr;
    const int brow = wc * 64 + fr;

    for (int kt = 0; kt < K_TOT / BK; ++kt) {
        const int k0 = kt * BK;
        // ---- stage A (128x32 f32 -> bf16) and B tile ----
#pragma unroll
        for (int s = 0; s < 4; ++s) {
            const int idx = s * 256 + tid;       // 0..1023 float4 slots
            const int row = idx >> 3;            // 8 float4 per row (32 f32)
            const int col = (idx & 7) << 2;
            f32x4 va = *reinterpret_cast<const f32x4*>(Ap + (size_t)row * K_TOT + k0 + col);
            f32x4 vb = *reinterpret_cast<const f32x4*>(Wp + (size_t)row * K_TOT + k0 + col);
            bf16x4 ha, hb;
#pragma unroll
            for (int j = 0; j < 4; ++j) { ha[j] = (bf16)va[j]; hb[j] = (bf16)vb[j]; }
            *reinterpret_cast<bf16x4*>(&As[row][col]) = ha;
            *reinterpret_cast<bf16x4*>(&Bs[row][col]) = hb;
        }
        __syncthreads();

        // ---- LDS -> fragments -> MFMA ----
        bf16x8 af[4], bfr[4];
#pragma unroll
        for (int m = 0; m < 4; ++m)
            af[m] = *reinterpret_cast<const bf16x8*>(&As[arow + m * 16][fk]);
#pragma unroll
        for (int n = 0; n < 4; ++n)
            bfr[n] = *reinterpret_cast<const bf16x8*>(&Bs[brow + n * 16][fk]);
#pragma unroll
        for (int m = 0; m < 4; ++m)
#pragma unroll
            for (int n = 0; n < 4; ++n)
                acc[m][n] = __builtin_amdgcn_mfma_f32_16x16x32_bf16(af[m], bfr[n], acc[m][n], 0, 0, 0);
        __syncthreads();
    }

    // ---- epilogue: bias (+ exp for logvar head), write f32 ----
    // C/D layout: col = lane&15, row = (lane>>4)*4 + j  [m89 verified]
#pragma unroll
    for (int m = 0; m < 4; ++m) {
        const int rbase = bm * BM + wr * 64 + m * 16 + (lane >> 4) * 4;
#pragma unroll
        for (int n = 0; n < 4; ++n) {
            const int c = cbase + wc * 64 + n * 16 + (lane & 15);
            const float bv = bias[c];
#pragma unroll
            for (int j = 0; j < 4; ++j) {
                float v = acc[m][n][j] + bv;
                if (!is_mu) v = __expf(0.5f * v);
                obase[(size_t)(rbase + j) * D_EMB + c] = v;
            }
        }
    }
}

extern "C" void kernel_launch(void* const* d_in, const int* in_sizes, int n_in,
                              void* d_out, int out_size, void* d_ws, size_t ws_size,
                              hipStream_t stream) {
    const float* x        = (const float*)d_in[0];
    const float* W_mu     = (const float*)d_in[1];
    const float* b_mu     = (const float*)d_in[2];
    const float* W_logvar = (const float*)d_in[3];
    const float* b_logvar = (const float*)d_in[4];
    float* out = (float*)d_out;

    dim3 grid((M_TOT / BM) * (E_TOT / BN));  // 128 * 8 = 1024 blocks
    gpe_gemm<<<grid, 256, 0, stream>>>(x, W_mu, b_mu, W_logvar, b_logvar, out);
}

// Round 2
// 75.853 us; speedup vs baseline: 1.3280x; 1.3280x over previous
//
#include <hip/hip_runtime.h>
#include <hip/hip_bf16.h>
#include <math.h>

typedef __bf16 bf16;
typedef __attribute__((ext_vector_type(4))) float f32x4;
typedef __attribute__((ext_vector_type(8))) bf16 bf16x8;
typedef __attribute__((ext_vector_type(4))) bf16 bf16x4;

#define M_TOT 16384
#define K_TOT 1024
#define E_TOT 1024   // 512 mu + 512 logvar
#define D_EMB 512

// ============================================================
// Pass 1: f32 -> bf16 convert (grid-stride, 8 elems/thread/iter)
// ============================================================
__global__ __launch_bounds__(256) void cvt_f32_bf16(const float* __restrict__ src,
                                                    bf16* __restrict__ dst, int n8) {
    int i = blockIdx.x * blockDim.x + threadIdx.x;
    const int stride = gridDim.x * blockDim.x;
    for (; i < n8; i += stride) {
        f32x4 a = ((const f32x4*)src)[2 * i];
        f32x4 b = ((const f32x4*)src)[2 * i + 1];
        bf16x8 o;
        o[0] = (bf16)a[0]; o[1] = (bf16)a[1]; o[2] = (bf16)a[2]; o[3] = (bf16)a[3];
        o[4] = (bf16)b[0]; o[5] = (bf16)b[1]; o[6] = (bf16)b[2]; o[7] = (bf16)b[3];
        ((bf16x8*)dst)[i] = o;
    }
}

// ============================================================
// Pass 2: bf16 GEMM, m97 structure (128x128 tile, BK=32,
// global_load_lds width=16, linear LDS, 4 waves 4x4 frags)
// ============================================================
__global__ __launch_bounds__(256) void gpe_gemm_bf16(
    const bf16* __restrict__ xb,     // [16384][1024]
    const bf16* __restrict__ Wb,     // [1024][1024] (mu rows 0..511, logvar 512..1023)
    const float* __restrict__ b_mu,
    const float* __restrict__ b_logvar,
    float* __restrict__ out)         // [2][16384][512]
{
    __shared__ __align__(16) bf16 As[128 * 32];   // linear, 64 B/row
    __shared__ __align__(16) bf16 Bs[128 * 32];

    const int tid  = threadIdx.x;
    const int lane = tid & 63;
    const int wid  = tid >> 6;
    const int wr   = wid >> 1;
    const int wc   = wid & 1;

    // XCD-bijective swizzle: same-bm blocks share an XCD (A-panel L2 reuse).
    // grid = 1024, 8 XCDs, round-robin assignment assumed (perf-only).
    const int b    = blockIdx.x;
    const int xcd  = b & 7;
    const int slot = b >> 3;          // 0..127 within XCD
    const int bn   = slot & 7;        // bn inner: 8 consecutive slots share bm? no:
    const int bm   = (slot >> 3) * 8 + xcd;  // 16 bm values per XCD, all 8 bn each

    const bf16* __restrict__ Ap = xb + (size_t)(bm * 128) * K_TOT;
    const bf16* __restrict__ Bp = Wb + (size_t)(bn * 128) * K_TOT;

    // global_load_lds staging geometry: per wave 2 calls x 64 lanes x 16 B = 2 KB.
    // flat LDS byte off = wid*2048 + q*1024 + lane*16 ; 64 B per row.
    int srow[2], scol[2];
#pragma unroll
    for (int q = 0; q < 2; ++q) {
        const int fo = wid * 2048 + q * 1024 + lane * 16;
        srow[q] = fo >> 6;          // 0..127
        scol[q] = (fo & 63) >> 1;   // elem offset 0/8/16/24
    }
    bf16* AsBase0 = As + wid * 1024;            // elems; +q*512
    bf16* BsBase0 = Bs + wid * 1024;

    f32x4 acc[4][4];
#pragma unroll
    for (int m = 0; m < 4; ++m)
#pragma unroll
        for (int n = 0; n < 4; ++n)
            acc[m][n] = (f32x4){0.f, 0.f, 0.f, 0.f};

    const int fr = lane & 15;
    const int fk = (lane >> 4) * 8;
    const int arow = wr * 64 + fr;
    const int brow = wc * 64 + fr;

    for (int k0 = 0; k0 < K_TOT; k0 += 32) {
#pragma unroll
        for (int q = 0; q < 2; ++q) {
            __builtin_amdgcn_global_load_lds(
                (__attribute__((address_space(1))) void*)(Ap + (size_t)srow[q] * K_TOT + k0 + scol[q]),
                (__attribute__((address_space(3))) void*)(AsBase0 + q * 512), 16, 0, 0);
            __builtin_amdgcn_global_load_lds(
                (__attribute__((address_space(1))) void*)(Bp + (size_t)srow[q] * K_TOT + k0 + scol[q]),
                (__attribute__((address_space(3))) void*)(BsBase0 + q * 512), 16, 0, 0);
        }
        __syncthreads();   // compiler emits vmcnt(0) drain before barrier

        bf16x8 af[4], bfv[4];
#pragma unroll
        for (int m = 0; m < 4; ++m)
            af[m] = *reinterpret_cast<const bf16x8*>(&As[(arow + m * 16) * 32 + fk]);
#pragma unroll
        for (int n = 0; n < 4; ++n)
            bfv[n] = *reinterpret_cast<const bf16x8*>(&Bs[(brow + n * 16) * 32 + fk]);
#pragma unroll
        for (int m = 0; m < 4; ++m)
#pragma unroll
            for (int n = 0; n < 4; ++n)
                acc[m][n] = __builtin_amdgcn_mfma_f32_16x16x32_bf16(af[m], bfv[n], acc[m][n], 0, 0, 0);
        __syncthreads();
    }

    // Epilogue: bias (+ exp for logvar head). C/D: col=lane&15, row=(lane>>4)*4+j.
    const int ebase = bn * 128;
    const bool is_mu = (ebase < D_EMB);
    const float* __restrict__ bias = is_mu ? b_mu : b_logvar;
    const int cbase = is_mu ? ebase : (ebase - D_EMB);
    float* __restrict__ obase = is_mu ? out : (out + (size_t)M_TOT * D_EMB);

#pragma unroll
    for (int m = 0; m < 4; ++m) {
        const int rbase = bm * 128 + wr * 64 + m * 16 + (lane >> 4) * 4;
#pragma unroll
        for (int n = 0; n < 4; ++n) {
            const int c = cbase + wc * 64 + n * 16 + (lane & 15);
            const float bv = bias[c];
#pragma unroll
            for (int j = 0; j < 4; ++j) {
                float v = acc[m][n][j] + bv;
                if (!is_mu) v = __expf(0.5f * v);
                obase[(size_t)(rbase + j) * D_EMB + c] = v;
            }
        }
    }
}

// ============================================================
// Fallback (round-1 kernel): single-pass f32-staging GEMM,
// used only if ws_size is too small for the bf16 scratch.
// ============================================================
#define LDS_STRIDE 40
__global__ __launch_bounds__(256) void gpe_gemm_fb(
    const float* __restrict__ x, const float* __restrict__ W_mu,
    const float* __restrict__ b_mu, const float* __restrict__ W_logvar,
    const float* __restrict__ b_logvar, float* __restrict__ out)
{
    __shared__ __align__(16) bf16 As[128][LDS_STRIDE];
    __shared__ __align__(16) bf16 Bs[128][LDS_STRIDE];
    const int tid = threadIdx.x, lane = tid & 63, wid = tid >> 6;
    const int wr = wid >> 1, wc = wid & 1;
    const int bn = blockIdx.x & 7, bm = blockIdx.x >> 3;
    const int ebase = bn * 128;
    const bool is_mu = (ebase < D_EMB);
    const float* Wp = is_mu ? (W_mu + (size_t)ebase * K_TOT)
                            : (W_logvar + (size_t)(ebase - D_EMB) * K_TOT);
    const float* bias = is_mu ? b_mu : b_logvar;
    const int cbase = is_mu ? ebase : (ebase - D_EMB);
    float* obase = is_mu ? out : (out + (size_t)M_TOT * D_EMB);
    const float* Ap = x + (size_t)(bm * 128) * K_TOT;
    f32x4 acc[4][4];
#pragma unroll
    for (int m = 0; m < 4; ++m)
#pragma unroll
        for (int n = 0; n < 4; ++n) acc[m][n] = (f32x4){0.f, 0.f, 0.f, 0.f};
    const int fr = lane & 15, fk = (lane >> 4) * 8;
    const int arow = wr * 64 + fr, brow = wc * 64 + fr;
    for (int kt = 0; kt < K_TOT / 32; ++kt) {
        const int k0 = kt * 32;
#pragma unroll
        for (int s = 0; s < 4; ++s) {
            const int idx = s * 256 + tid;
            const int row = idx >> 3, col = (idx & 7) << 2;
            f32x4 va = *reinterpret_cast<const f32x4*>(Ap + (size_t)row * K_TOT + k0 + col);
            f32x4 vb = *reinterpret_cast<const f32x4*>(Wp + (size_t)row * K_TOT + k0 + col);
            bf16x4 ha, hb;
#pragma unroll
            for (int j = 0; j < 4; ++j) { ha[j] = (bf16)va[j]; hb[j] = (bf16)vb[j]; }
            *reinterpret_cast<bf16x4*>(&As[row][col]) = ha;
            *reinterpret_cast<bf16x4*>(&Bs[row][col]) = hb;
        }
        __syncthreads();
        bf16x8 af[4], bfv[4];
#pragma unroll
        for (int m = 0; m < 4; ++m)
            af[m] = *reinterpret_cast<const bf16x8*>(&As[arow + m * 16][fk]);
#pragma unroll
        for (int n = 0; n < 4; ++n)
            bfv[n] = *reinterpret_cast<const bf16x8*>(&Bs[brow + n * 16][fk]);
#pragma unroll
        for (int m = 0; m < 4; ++m)
#pragma unroll
            for (int n = 0; n < 4; ++n)
                acc[m][n] = __builtin_amdgcn_mfma_f32_16x16x32_bf16(af[m], bfv[n], acc[m][n], 0, 0, 0);
        __syncthreads();
    }
#pragma unroll
    for (int m = 0; m < 4; ++m) {
        const int rbase = bm * 128 + wr * 64 + m * 16 + (lane >> 4) * 4;
#pragma unroll
        for (int n = 0; n < 4; ++n) {
            const int c = cbase + wc * 64 + n * 16 + (lane & 15);
            const float bv = bias[c];
#pragma unroll
            for (int j = 0; j < 4; ++j) {
                float v = acc[m][n][j] + bv;
                if (!is_mu) v = __expf(0.5f * v);
                obase[(size_t)(rbase + j) * D_EMB + c] = v;
            }
        }
    }
}

extern "C" void kernel_launch(void* const* d_in, const int* in_sizes, int n_in,
                              void* d_out, int out_size, void* d_ws, size_t ws_size,
                              hipStream_t stream) {
    const float* x        = (const float*)d_in[0];
    const float* W_mu     = (const float*)d_in[1];
    const float* b_mu     = (const float*)d_in[2];
    const float* W_logvar = (const float*)d_in[3];
    const float* b_logvar = (const float*)d_in[4];
    float* out = (float*)d_out;

    const size_t n_x = (size_t)M_TOT * K_TOT;          // 16.78M
    const size_t n_w = (size_t)D_EMB * K_TOT;          // 0.52M per head
    const size_t ws_needed = (n_x + 2 * n_w) * sizeof(bf16);  // 35.65 MB

    if (ws_size >= ws_needed) {
        bf16* xb = (bf16*)d_ws;
        bf16* Wb = xb + n_x;
        cvt_f32_bf16<<<2048, 256, 0, stream>>>(x, xb, (int)(n_x / 8));
        cvt_f32_bf16<<<256, 256, 0, stream>>>(W_mu, Wb, (int)(n_w / 8));
        cvt_f32_bf16<<<256, 256, 0, stream>>>(W_logvar, Wb + n_w, (int)(n_w / 8));
        gpe_gemm_bf16<<<1024, 256, 0, stream>>>(xb, Wb, b_mu, b_logvar, out);
    } else {
        gpe_gemm_fb<<<1024, 256, 0, stream>>>(x, W_mu, b_mu, W_logvar, b_logvar, out);
    }
}

// Round 3
// 63.440 us; speedup vs baseline: 1.5878x; 1.1957x over previous
//
#include <hip/hip_runtime.h>
#include <hip/hip_bf16.h>
#include <math.h>

typedef __bf16 bf16;
typedef __attribute__((ext_vector_type(4))) float f32x4;
typedef __attribute__((ext_vector_type(8))) bf16 bf16x8;
typedef __attribute__((ext_vector_type(4))) bf16 bf16x4;

#define M_TOT 16384
#define K_TOT 1024
#define E_TOT 1024   // 512 mu + 512 logvar
#define D_EMB 512
#define BMN 256
#define BK 32
#define NT (K_TOT / BK)   // 32

// ============================================================
// Pass 1: f32 -> bf16 convert
// ============================================================
__global__ __launch_bounds__(256) void cvt_f32_bf16(const float* __restrict__ src,
                                                    bf16* __restrict__ dst, int n8) {
    int i = blockIdx.x * blockDim.x + threadIdx.x;
    const int stride = gridDim.x * blockDim.x;
    for (; i < n8; i += stride) {
        f32x4 a = ((const f32x4*)src)[2 * i];
        f32x4 b = ((const f32x4*)src)[2 * i + 1];
        bf16x8 o;
        o[0] = (bf16)a[0]; o[1] = (bf16)a[1]; o[2] = (bf16)a[2]; o[3] = (bf16)a[3];
        o[4] = (bf16)b[0]; o[5] = (bf16)b[1]; o[6] = (bf16)b[2]; o[7] = (bf16)b[3];
        ((bf16x8*)dst)[i] = o;
    }
}

// ============================================================
// Pass 2: 256x256 tile, BK=32, 8 waves (2M x 4N), counted-vmcnt
// phase schedule + T2 LDS swizzle + T5 setprio.
// LDS: 2 bufs x (A 256x32 + B 256x32) bf16 = 65536 B.
// Swizzle: linear LDS byte o, row = o>>6; stored-at o holds global
// data for column (o&63) ^ (((row>>1)&3)<<4); reads apply same XOR.
// ============================================================
__global__ __launch_bounds__(512, 2) void gpe_gemm_256(
    const bf16* __restrict__ xb,     // [16384][1024]
    const bf16* __restrict__ Wb,     // [1024][1024]
    const float* __restrict__ b_mu,
    const float* __restrict__ b_logvar,
    float* __restrict__ out)
{
    __shared__ __align__(16) bf16 lds[2 * 2 * BMN * BK];   // 65536 B

    const int tid  = threadIdx.x;
    const int lane = tid & 63;
    const int wid  = tid >> 6;        // 0..7
    const int wr   = wid >> 2;        // 0..1
    const int wc   = wid & 3;         // 0..3

    // T1: bijective XCD swizzle (nwg = 256, divisible by 8); bn inner.
    const int bid = blockIdx.x;
    const int swz = (bid & 7) * 32 + (bid >> 3);
    const int bn  = swz & 3;          // 0..3
    const int bm  = swz >> 2;         // 0..63

    const bf16* __restrict__ Ap = xb + (size_t)(bm * BMN) * K_TOT;
    const bf16* __restrict__ Bp = Wb + (size_t)(bn * BMN) * K_TOT;

    // ---- staging geometry (per thread, per op, call q in 0..1) ----
    // linear LDS byte o = q*8192 + wid*1024 + lane*16; row = o>>6 (64B rows)
    // inverse-swizzled global column slot: ((lane&3) ^ ((lane>>3)&3)) * 8 elems
    const int srow_l = wid * 16 + (lane >> 2);                 // + q*128
    const int gcol   = ((lane & 3) ^ ((lane >> 3) & 3)) * 8;   // elems

    // ---- fragment read geometry ----
    const int fr  = lane & 15;
    const int g16 = lane >> 4;        // 0..3
    // swizzled column (elems): (g16*16 ^ ((fr>>1 & 3)<<4)) bytes
    const int colx  = ((g16 * 16) ^ (((fr >> 1) & 3) << 4)) >> 1;
    const int arow0 = wr * 128 + fr;
    const int brow0 = wc * 64 + fr;

    f32x4 acc[8][4];
#pragma unroll
    for (int m = 0; m < 8; ++m)
#pragma unroll
        for (int n = 0; n < 4; ++n)
            acc[m][n] = (f32x4){0.f, 0.f, 0.f, 0.f};

    // stage one 16B/lane round: op 0 = A, 1 = B
    auto stage = [&](int buf, int op, int q, int kt) {
        const bf16* src = (op ? Bp : Ap)
                        + (size_t)(q * 128 + srow_l) * K_TOT + kt * BK + gcol;
        bf16* dst = lds + buf * 16384 + op * 8192 + q * 4096 + wid * 512;
        __builtin_amdgcn_global_load_lds(
            (const __attribute__((address_space(1))) void*)src,
            (__attribute__((address_space(3))) void*)dst, 16, 0, 0);
    };

    // prologue: stage tile 0 into buf 0 (4 loads/thread)
    stage(0, 0, 0, 0); stage(0, 0, 1, 0);
    stage(0, 1, 0, 0); stage(0, 1, 1, 0);

    for (int t = 0; t < NT; ++t) {
        const int buf = t & 1;
        const bf16* Abase = lds + buf * 16384;
        const bf16* Bbase = Abase + 8192;
        const bool have = (t + 1 < NT);

        // ---- prelude: issue 2 prefetch loads, counted wait, barrier ----
        if (have) {
            stage(buf ^ 1, 0, 0, t + 1);
            stage(buf ^ 1, 1, 0, t + 1);
            asm volatile("s_waitcnt vmcnt(2)" ::: "memory");
        } else {
            asm volatile("s_waitcnt vmcnt(0)" ::: "memory");
        }
        __builtin_amdgcn_s_barrier();

        // ---- phase 0: B frags (4) + A m0..3 (4); 16 MFMA ----
        bf16x8 bfv[4], af[4];
#pragma unroll
        for (int n = 0; n < 4; ++n)
            bfv[n] = *(const bf16x8*)&Bbase[(brow0 + n * 16) * 32 + colx];
#pragma unroll
        for (int m = 0; m < 4; ++m)
            af[m] = *(const bf16x8*)&Abase[(arow0 + m * 16) * 32 + colx];
        __builtin_amdgcn_s_setprio(1);
#pragma unroll
        for (int m = 0; m < 4; ++m)
#pragma unroll
            for (int n = 0; n < 4; ++n)
                acc[m][n] = __builtin_amdgcn_mfma_f32_16x16x32_bf16(af[m], bfv[n], acc[m][n], 0, 0, 0);
        __builtin_amdgcn_s_setprio(0);
        __builtin_amdgcn_s_barrier();

        // ---- phase 1: A m4..7 (4 reads); issue remaining 2 prefetch; 16 MFMA ----
        bf16x8 af2[4];
#pragma unroll
        for (int m = 0; m < 4; ++m)
            af2[m] = *(const bf16x8*)&Abase[(arow0 + (m + 4) * 16) * 32 + colx];
        if (have) {
            stage(buf ^ 1, 0, 1, t + 1);
            stage(buf ^ 1, 1, 1, t + 1);
        }
        __builtin_amdgcn_s_barrier();
        __builtin_amdgcn_s_setprio(1);
#pragma unroll
        for (int m = 0; m < 4; ++m)
#pragma unroll
            for (int n = 0; n < 4; ++n)
                acc[m + 4][n] = __builtin_amdgcn_mfma_f32_16x16x32_bf16(af2[m], bfv[n], acc[m + 4][n], 0, 0, 0);
        __builtin_amdgcn_s_setprio(0);
        __builtin_amdgcn_s_barrier();
    }

    // ---- epilogue ----
    const int ebase = bn * BMN;
    const bool is_mu = (ebase < D_EMB);
    const float* __restrict__ bias = is_mu ? b_mu : b_logvar;
    const int cbase = is_mu ? ebase : (ebase - D_EMB);
    float* __restrict__ obase = is_mu ? out : (out + (size_t)M_TOT * D_EMB);

#pragma unroll
    for (int m = 0; m < 8; ++m) {
        const int rbase = bm * BMN + wr * 128 + m * 16 + g16 * 4;
#pragma unroll
        for (int n = 0; n < 4; ++n) {
            const int c = cbase + wc * 64 + n * 16 + fr;
            const float bv = bias[c];
#pragma unroll
            for (int j = 0; j < 4; ++j) {
                float v = acc[m][n][j] + bv;
                if (!is_mu) v = __expf(0.5f * v);
                obase[(size_t)(rbase + j) * D_EMB + c] = v;
            }
        }
    }
}

// ============================================================
// Fallback: single-pass f32-staging GEMM (no workspace needed)
// ============================================================
#define LDS_STRIDE 40
__global__ __launch_bounds__(256) void gpe_gemm_fb(
    const float* __restrict__ x, const float* __restrict__ W_mu,
    const float* __restrict__ b_mu, const float* __restrict__ W_logvar,
    const float* __restrict__ b_logvar, float* __restrict__ out)
{
    __shared__ __align__(16) bf16 As[128][LDS_STRIDE];
    __shared__ __align__(16) bf16 Bs[128][LDS_STRIDE];
    const int tid = threadIdx.x, lane = tid & 63, wid = tid >> 6;
    const int wr = wid >> 1, wc = wid & 1;
    const int bn = blockIdx.x & 7, bm = blockIdx.x >> 3;
    const int ebase = bn * 128;
    const bool is_mu = (ebase < D_EMB);
    const float* Wp = is_mu ? (W_mu + (size_t)ebase * K_TOT)
                            : (W_logvar + (size_t)(ebase - D_EMB) * K_TOT);
    const float* bias = is_mu ? b_mu : b_logvar;
    const int cbase = is_mu ? ebase : (ebase - D_EMB);
    float* obase = is_mu ? out : (out + (size_t)M_TOT * D_EMB);
    const float* Ap = x + (size_t)(bm * 128) * K_TOT;
    f32x4 acc[4][4];
#pragma unroll
    for (int m = 0; m < 4; ++m)
#pragma unroll
        for (int n = 0; n < 4; ++n) acc[m][n] = (f32x4){0.f, 0.f, 0.f, 0.f};
    const int fr = lane & 15, fk = (lane >> 4) * 8;
    const int arow = wr * 64 + fr, brow = wc * 64 + fr;
    for (int kt = 0; kt < K_TOT / 32; ++kt) {
        const int k0 = kt * 32;
#pragma unroll
        for (int s = 0; s < 4; ++s) {
            const int idx = s * 256 + tid;
            const int row = idx >> 3, col = (idx & 7) << 2;
            f32x4 va = *reinterpret_cast<const f32x4*>(Ap + (size_t)row * K_TOT + k0 + col);
            f32x4 vb = *reinterpret_cast<const f32x4*>(Wp + (size_t)row * K_TOT + k0 + col);
            bf16x4 ha, hb;
#pragma unroll
            for (int j = 0; j < 4; ++j) { ha[j] = (bf16)va[j]; hb[j] = (bf16)vb[j]; }
            *reinterpret_cast<bf16x4*>(&As[row][col]) = ha;
            *reinterpret_cast<bf16x4*>(&Bs[row][col]) = hb;
        }
        __syncthreads();
        bf16x8 af[4], bfv[4];
#pragma unroll
        for (int m = 0; m < 4; ++m)
            af[m] = *reinterpret_cast<const bf16x8*>(&As[arow + m * 16][fk]);
#pragma unroll
        for (int n = 0; n < 4; ++n)
            bfv[n] = *reinterpret_cast<const bf16x8*>(&Bs[brow + n * 16][fk]);
#pragma unroll
        for (int m = 0; m < 4; ++m)
#pragma unroll
            for (int n = 0; n < 4; ++n)
                acc[m][n] = __builtin_amdgcn_mfma_f32_16x16x32_bf16(af[m], bfv[n], acc[m][n], 0, 0, 0);
        __syncthreads();
    }
#pragma unroll
    for (int m = 0; m < 4; ++m) {
        const int rbase = bm * 128 + wr * 64 + m * 16 + (lane >> 4) * 4;
#pragma unroll
        for (int n = 0; n < 4; ++n) {
            const int c = cbase + wc * 64 + n * 16 + (lane & 15);
            const float bv = bias[c];
#pragma unroll
            for (int j = 0; j < 4; ++j) {
                float v = acc[m][n][j] + bv;
                if (!is_mu) v = __expf(0.5f * v);
                obase[(size_t)(rbase + j) * D_EMB + c] = v;
            }
        }
    }
}

extern "C" void kernel_launch(void* const* d_in, const int* in_sizes, int n_in,
                              void* d_out, int out_size, void* d_ws, size_t ws_size,
                              hipStream_t stream) {
    const float* x        = (const float*)d_in[0];
    const float* W_mu     = (const float*)d_in[1];
    const float* b_mu     = (const float*)d_in[2];
    const float* W_logvar = (const float*)d_in[3];
    const float* b_logvar = (const float*)d_in[4];
    float* out = (float*)d_out;

    const size_t n_x = (size_t)M_TOT * K_TOT;
    const size_t n_w = (size_t)D_EMB * K_TOT;
    const size_t ws_needed = (n_x + 2 * n_w) * sizeof(bf16);

    if (ws_size >= ws_needed) {
        bf16* xb = (bf16*)d_ws;
        bf16* Wb = xb + n_x;
        cvt_f32_bf16<<<2048, 256, 0, stream>>>(x, xb, (int)(n_x / 8));
        cvt_f32_bf16<<<256, 256, 0, stream>>>(W_mu, Wb, (int)(n_w / 8));
        cvt_f32_bf16<<<256, 256, 0, stream>>>(W_logvar, Wb + n_w, (int)(n_w / 8));
        gpe_gemm_256<<<256, 512, 0, stream>>>(xb, Wb, b_mu, b_logvar, out);
    } else {
        gpe_gemm_fb<<<1024, 256, 0, stream>>>(x, W_mu, b_mu, W_logvar, b_logvar, out);
    }
}

// Round 4
// 59.376 us; speedup vs baseline: 1.6965x; 1.0684x over previous
//
#include <hip/hip_runtime.h>
#include <hip/hip_bf16.h>
#include <math.h>

typedef __bf16 bf16;
typedef __attribute__((ext_vector_type(4))) float f32x4;
typedef __attribute__((ext_vector_type(8))) bf16 bf16x8;
typedef __attribute__((ext_vector_type(4))) bf16 bf16x4;

#define M_TOT 16384
#define K_TOT 1024
#define E_TOT 1024   // 512 mu + 512 logvar
#define D_EMB 512
#define NTILES 16    // K_TOT / 64

// ============================================================
// Pass 1: fused f32 -> bf16 convert of x, W_mu, W_logvar
// ============================================================
__global__ __launch_bounds__(256) void cvt_all(
    const float* __restrict__ x, const float* __restrict__ wmu,
    const float* __restrict__ wlv, bf16* __restrict__ xb, bf16* __restrict__ wb)
{
    const int NX8 = (M_TOT * K_TOT) / 8;   // 2097152
    const int NW8 = (D_EMB * K_TOT) / 8;   // 65536
    const int TOT = NX8 + 2 * NW8;
    int i = blockIdx.x * blockDim.x + threadIdx.x;
    const int stride = gridDim.x * blockDim.x;
    for (; i < TOT; i += stride) {
        const float* s;
        bf16* d;
        if (i < NX8)            { s = x   + (size_t)i * 8;          d = xb + (size_t)i * 8; }
        else if (i < NX8 + NW8) { s = wmu + (size_t)(i - NX8) * 8;  d = wb + (size_t)(i - NX8) * 8; }
        else                    { s = wlv + (size_t)(i - NX8 - NW8) * 8; d = wb + (size_t)(i - NX8) * 8; }
        f32x4 a = ((const f32x4*)s)[0];
        f32x4 b = ((const f32x4*)s)[1];
        bf16x8 o;
        o[0] = (bf16)a[0]; o[1] = (bf16)a[1]; o[2] = (bf16)a[2]; o[3] = (bf16)a[3];
        o[4] = (bf16)b[0]; o[5] = (bf16)b[1]; o[6] = (bf16)b[2]; o[7] = (bf16)b[3];
        *(bf16x8*)d = o;
    }
}

// ============================================================
// Pass 2: 256x256 tile, BK=64, 8 waves, 8-phase counted-vmcnt
// schedule (T3+T4) + LDS XOR swizzle (T2) + setprio (T5) +
// bijective XCD swizzle (T1).
// LDS: [2 buf][2 op][256 rows][64 elems] bf16 = 131072 B.
// Swizzle: LDS(row, c) holds global(row, c ^ ((row&7)<<3)) [elems];
// inverse applied on global source (global_load_lds dest stays linear).
// Wave mapping: A row = m*32 + wr*16 + fr  (m0-3 -> rows 0-127 = half A0)
//               B row = n*64 + wc*16 + fr  (n0-1 -> rows 0-127 = half B0)
// so each phase reads exactly one half-tile region:
//   ph0: A-h0 (8 rd) + B-h0 (4 rd), MFMA m0-3 x n0-1
//   ph1: B-h1 (4 rd),               MFMA m0-3 x n2-3
//   ph2: A-h1 (8 rd),               MFMA m4-7 x n2-3
//   ph3: no reads,                  MFMA m4-7 x n0-1
// Stage schedule (1 half/phase, region freed >=1 barrier earlier):
//   ph0: (t+1, A-h1)   ph1: (t+2, A-h0)   ph2: (t+2, B-h0)   ph3: (t+2, B-h1)
// vmcnt(6) before ph3's trailing barrier: with 7 halves (14 loads) max
// outstanding, drains the 4 oldest = all of tile t+1. Steady state: 3
// halves in flight. Tail: t+2>=NT -> vmcnt(0) drains tile 15.
// ============================================================
__global__ __launch_bounds__(512, 2) void gpe_gemm8(
    const bf16* __restrict__ xb,     // [16384][1024]
    const bf16* __restrict__ Wb,     // [1024][1024]
    const float* __restrict__ b_mu,
    const float* __restrict__ b_logvar,
    float* __restrict__ out)         // [2][16384][512]
{
    __shared__ __align__(16) bf16 lds[2 * 2 * 256 * 64];   // 131072 B

    const int tid  = threadIdx.x;
    const int lane = tid & 63;
    const int wid  = tid >> 6;        // 0..7
    const int wr   = wid >> 2;        // 0..1
    const int wc   = wid & 3;         // 0..3

    // T1: bijective XCD swizzle (nwg=256, 32/XCD); bn inner per XCD.
    const int bid = blockIdx.x;
    const int swz = (bid & 7) * 32 + (bid >> 3);
    const int bn  = swz & 3;          // 0..3
    const int bm  = swz >> 2;         // 0..63

    const bf16* __restrict__ Ap = xb + (size_t)(bm * 256) * K_TOT;
    const bf16* __restrict__ Bp = Wb + (size_t)(bn * 256) * K_TOT;

    // staging constants: thread covers row srow of each 64-row q-slice,
    // global col pre-inverse-swizzled so LDS dest stays linear.
    const int srow = wid * 8 + (lane >> 3);                   // 0..63
    const int scol = ((lane & 7) ^ (lane >> 3)) << 3;         // elems
    const int sdst = wid * 512;                               // elems (lane*8 added by HW)

    // read constants
    const int fr    = lane & 15;
    const int g16   = lane >> 4;
    const int colk0 = (g16 * 8) ^ ((fr & 7) << 3);            // elems, kk=0; kk=1 -> ^32
    const int rA    = wr * 16 + fr;                           // + m*32
    const int rB    = wc * 16 + fr;                           // + n*64

    f32x4 acc[8][4];
#pragma unroll
    for (int m = 0; m < 8; ++m)
#pragma unroll
        for (int n = 0; n < 4; ++n)
            acc[m][n] = (f32x4){0.f, 0.f, 0.f, 0.f};

    // stage one half-tile: h = 0:A-h0 1:A-h1 2:B-h0 3:B-h1 (2 x 16B/lane)
    auto stage = [&](int tile, int h) {
        if (tile >= NTILES) return;
        const int op = h >> 1, hh = h & 1;
        const int buf = tile & 1;
        const bf16* base = op ? Bp : Ap;
#pragma unroll
        for (int q = 0; q < 2; ++q) {
            const bf16* s = base + (size_t)(hh * 128 + q * 64 + srow) * K_TOT + tile * 64 + scol;
            bf16* d = lds + buf * 32768 + op * 16384 + hh * 8192 + q * 4096 + sdst;
            __builtin_amdgcn_global_load_lds(
                (const __attribute__((address_space(1))) void*)s,
                (__attribute__((address_space(3))) void*)d, 16, 0, 0);
        }
    };

    // ---- prologue: tile0 all halves; tile1 h0,h2,h3 ----
    stage(0, 0); stage(0, 1); stage(0, 2); stage(0, 3);
    asm volatile("s_waitcnt vmcnt(4)" ::: "memory");
    stage(1, 0); stage(1, 2); stage(1, 3);
    asm volatile("s_waitcnt vmcnt(6)" ::: "memory");
    __builtin_amdgcn_s_barrier();

#pragma unroll 2
    for (int t = 0; t < NTILES; ++t) {
        const int buf = t & 1;
        const bf16* Ab = lds + buf * 32768;
        const bf16* Bb = Ab + 16384;

        bf16x8 af[4][2], bv[4][2];

        // ---------------- phase 0 ----------------
#pragma unroll
        for (int m = 0; m < 4; ++m) {
            af[m][0] = *(const bf16x8*)&Ab[(m * 32 + rA) * 64 + colk0];
            af[m][1] = *(const bf16x8*)&Ab[(m * 32 + rA) * 64 + (colk0 ^ 32)];
        }
#pragma unroll
        for (int n = 0; n < 2; ++n) {
            bv[n][0] = *(const bf16x8*)&Bb[(n * 64 + rB) * 64 + colk0];
            bv[n][1] = *(const bf16x8*)&Bb[(n * 64 + rB) * 64 + (colk0 ^ 32)];
        }
        stage(t + 1, 1);
        __builtin_amdgcn_s_barrier();
        asm volatile("s_waitcnt lgkmcnt(0)" ::: "memory");
        __builtin_amdgcn_s_setprio(1);
#pragma unroll
        for (int m = 0; m < 4; ++m)
#pragma unroll
            for (int n = 0; n < 2; ++n) {
                acc[m][n] = __builtin_amdgcn_mfma_f32_16x16x32_bf16(af[m][0], bv[n][0], acc[m][n], 0, 0, 0);
                acc[m][n] = __builtin_amdgcn_mfma_f32_16x16x32_bf16(af[m][1], bv[n][1], acc[m][n], 0, 0, 0);
            }
        __builtin_amdgcn_s_setprio(0);
        __builtin_amdgcn_s_barrier();

        // ---------------- phase 1 ----------------
#pragma unroll
        for (int n = 2; n < 4; ++n) {
            bv[n][0] = *(const bf16x8*)&Bb[(n * 64 + rB) * 64 + colk0];
            bv[n][1] = *(const bf16x8*)&Bb[(n * 64 + rB) * 64 + (colk0 ^ 32)];
        }
        stage(t + 2, 0);
        __builtin_amdgcn_s_barrier();
        asm volatile("s_waitcnt lgkmcnt(0)" ::: "memory");
        __builtin_amdgcn_s_setprio(1);
#pragma unroll
        for (int m = 0; m < 4; ++m)
#pragma unroll
            for (int n = 2; n < 4; ++n) {
                acc[m][n] = __builtin_amdgcn_mfma_f32_16x16x32_bf16(af[m][0], bv[n][0], acc[m][n], 0, 0, 0);
                acc[m][n] = __builtin_amdgcn_mfma_f32_16x16x32_bf16(af[m][1], bv[n][1], acc[m][n], 0, 0, 0);
            }
        __builtin_amdgcn_s_setprio(0);
        __builtin_amdgcn_s_barrier();

        // ---------------- phase 2 ----------------
#pragma unroll
        for (int m = 0; m < 4; ++m) {
            af[m][0] = *(const bf16x8*)&Ab[((m + 4) * 32 + rA) * 64 + colk0];
            af[m][1] = *(const bf16x8*)&Ab[((m + 4) * 32 + rA) * 64 + (colk0 ^ 32)];
        }
        stage(t + 2, 2);
        __builtin_amdgcn_s_barrier();
        asm volatile("s_waitcnt lgkmcnt(0)" ::: "memory");
        __builtin_amdgcn_s_setprio(1);
#pragma unroll
        for (int m = 0; m < 4; ++m)
#pragma unroll
            for (int n = 2; n < 4; ++n) {
                acc[m + 4][n] = __builtin_amdgcn_mfma_f32_16x16x32_bf16(af[m][0], bv[n][0], acc[m + 4][n], 0, 0, 0);
                acc[m + 4][n] = __builtin_amdgcn_mfma_f32_16x16x32_bf16(af[m][1], bv[n][1], acc[m + 4][n], 0, 0, 0);
            }
        __builtin_amdgcn_s_setprio(0);
        __builtin_amdgcn_s_barrier();

        // ---------------- phase 3 ----------------
        stage(t + 2, 3);
        __builtin_amdgcn_s_barrier();
        __builtin_amdgcn_s_setprio(1);
#pragma unroll
        for (int m = 0; m < 4; ++m)
#pragma unroll
            for (int n = 0; n < 2; ++n) {
                acc[m + 4][n] = __builtin_amdgcn_mfma_f32_16x16x32_bf16(af[m][0], bv[n][0], acc[m + 4][n], 0, 0, 0);
                acc[m + 4][n] = __builtin_amdgcn_mfma_f32_16x16x32_bf16(af[m][1], bv[n][1], acc[m + 4][n], 0, 0, 0);
            }
        __builtin_amdgcn_s_setprio(0);
        if (t + 2 < NTILES)      asm volatile("s_waitcnt vmcnt(6)" ::: "memory");
        else if (t + 1 < NTILES) asm volatile("s_waitcnt vmcnt(0)" ::: "memory");
        __builtin_amdgcn_s_barrier();
    }

    // ---- epilogue: bias (+ exp for logvar head) ----
    const bool is_mu = (bn < 2);
    const float* __restrict__ bias = is_mu ? b_mu : b_logvar;
    const int cb = (bn & 1) * 256;
    float* __restrict__ obase = is_mu ? out : (out + (size_t)M_TOT * D_EMB);

#pragma unroll
    for (int m = 0; m < 8; ++m) {
        const int row0 = bm * 256 + m * 32 + wr * 16 + g16 * 4;
#pragma unroll
        for (int n = 0; n < 4; ++n) {
            const int c = cb + n * 64 + wc * 16 + fr;
            const float bvs = bias[c];
#pragma unroll
            for (int j = 0; j < 4; ++j) {
                float v = acc[m][n][j] + bvs;
                if (!is_mu) v = __expf(0.5f * v);
                obase[(size_t)(row0 + j) * D_EMB + c] = v;
            }
        }
    }
}

// ============================================================
// Fallback: single-pass f32-staging GEMM (no workspace needed)
// ============================================================
#define LDS_STRIDE 40
__global__ __launch_bounds__(256) void gpe_gemm_fb(
    const float* __restrict__ x, const float* __restrict__ W_mu,
    const float* __restrict__ b_mu, const float* __restrict__ W_logvar,
    const float* __restrict__ b_logvar, float* __restrict__ out)
{
    __shared__ __align__(16) bf16 As[128][LDS_STRIDE];
    __shared__ __align__(16) bf16 Bs[128][LDS_STRIDE];
    const int tid = threadIdx.x, lane = tid & 63, wid = tid >> 6;
    const int wr = wid >> 1, wc = wid & 1;
    const int bn = blockIdx.x & 7, bm = blockIdx.x >> 3;
    const int ebase = bn * 128;
    const bool is_mu = (ebase < D_EMB);
    const float* Wp = is_mu ? (W_mu + (size_t)ebase * K_TOT)
                            : (W_logvar + (size_t)(ebase - D_EMB) * K_TOT);
    const float* bias = is_mu ? b_mu : b_logvar;
    const int cbase = is_mu ? ebase : (ebase - D_EMB);
    float* obase = is_mu ? out : (out + (size_t)M_TOT * D_EMB);
    const float* Ap = x + (size_t)(bm * 128) * K_TOT;
    f32x4 acc[4][4];
#pragma unroll
    for (int m = 0; m < 4; ++m)
#pragma unroll
        for (int n = 0; n < 4; ++n) acc[m][n] = (f32x4){0.f, 0.f, 0.f, 0.f};
    const int fr = lane & 15, fk = (lane >> 4) * 8;
    const int arow = wr * 64 + fr, brow = wc * 64 + fr;
    for (int kt = 0; kt < K_TOT / 32; ++kt) {
        const int k0 = kt * 32;
#pragma unroll
        for (int s = 0; s < 4; ++s) {
            const int idx = s * 256 + tid;
            const int row = idx >> 3, col = (idx & 7) << 2;
            f32x4 va = *reinterpret_cast<const f32x4*>(Ap + (size_t)row * K_TOT + k0 + col);
            f32x4 vb = *reinterpret_cast<const f32x4*>(Wp + (size_t)row * K_TOT + k0 + col);
            bf16x4 ha, hb;
#pragma unroll
            for (int j = 0; j < 4; ++j) { ha[j] = (bf16)va[j]; hb[j] = (bf16)vb[j]; }
            *reinterpret_cast<bf16x4*>(&As[row][col]) = ha;
            *reinterpret_cast<bf16x4*>(&Bs[row][col]) = hb;
        }
        __syncthreads();
        bf16x8 af[4], bfv[4];
#pragma unroll
        for (int m = 0; m < 4; ++m)
            af[m] = *reinterpret_cast<const bf16x8*>(&As[arow + m * 16][fk]);
#pragma unroll
        for (int n = 0; n < 4; ++n)
            bfv[n] = *reinterpret_cast<const bf16x8*>(&Bs[brow + n * 16][fk]);
#pragma unroll
        for (int m = 0; m < 4; ++m)
#pragma unroll
            for (int n = 0; n < 4; ++n)
                acc[m][n] = __builtin_amdgcn_mfma_f32_16x16x32_bf16(af[m], bfv[n], acc[m][n], 0, 0, 0);
        __syncthreads();
    }
#pragma unroll
    for (int m = 0; m < 4; ++m) {
        const int rbase = bm * 128 + wr * 64 + m * 16 + (lane >> 4) * 4;
#pragma unroll
        for (int n = 0; n < 4; ++n) {
            const int c = cbase + wc * 64 + n * 16 + (lane & 15);
            const float bv = bias[c];
#pragma unroll
            for (int j = 0; j < 4; ++j) {
                float v = acc[m][n][j] + bv;
                if (!is_mu) v = __expf(0.5f * v);
                obase[(size_t)(rbase + j) * D_EMB + c] = v;
            }
        }
    }
}

extern "C" void kernel_launch(void* const* d_in, const int* in_sizes, int n_in,
                              void* d_out, int out_size, void* d_ws, size_t ws_size,
                              hipStream_t stream) {
    const float* x        = (const float*)d_in[0];
    const float* W_mu     = (const float*)d_in[1];
    const float* b_mu     = (const float*)d_in[2];
    const float* W_logvar = (const float*)d_in[3];
    const float* b_logvar = (const float*)d_in[4];
    float* out = (float*)d_out;

    const size_t n_x = (size_t)M_TOT * K_TOT;
    const size_t n_w = (size_t)D_EMB * K_TOT;
    const size_t ws_needed = (n_x + 2 * n_w) * sizeof(bf16);

    if (ws_size >= ws_needed) {
        bf16* xb = (bf16*)d_ws;
        bf16* Wb = xb + n_x;
        cvt_all<<<2048, 256, 0, stream>>>(x, W_mu, W_logvar, xb, Wb);
        gpe_gemm8<<<256, 512, 0, stream>>>(xb, Wb, b_mu, b_logvar, out);
    } else {
        gpe_gemm_fb<<<1024, 256, 0, stream>>>(x, W_mu, b_mu, W_logvar, b_logvar, out);
    }
}